// Round 11
// baseline (391.274 us; speedup 1.0000x reference)
//
#include <hip/hip_runtime.h>
#include <hip/hip_bf16.h>
#include <cstdint>
#include <cstddef>

// Problem dims (compile-time)
constexpr int Bc = 8;
constexpr int Vc = 2048;   // S*T
constexpr int Pc = 512;
constexpr int Hc = 8;
constexpr int Lc = 2;
constexpr int ROWS_KV = Bc * Vc;   // 16384
constexpr int ROWS_AT = Bc * Pc;   // 4096

typedef __attribute__((ext_vector_type(8))) short bf16x8;   // 8 bf16 (4 VGPRs)
typedef __attribute__((ext_vector_type(4))) float f32x4;

static __device__ __forceinline__ unsigned short f2bf(float v) {
    __hip_bfloat16 h = __float2bfloat16(v);
    return *(unsigned short*)&h;
}
static __device__ __forceinline__ float bflo(unsigned int u) {
    return __uint_as_float(u << 16);
}
static __device__ __forceinline__ float bfhi(unsigned int u) {
    return __uint_as_float(u & 0xffff0000u);
}
// HW packed f32->bf16 (RNE), 1 inst per 2 elems
static __device__ __forceinline__ unsigned int cvt2(float lo, float hi) {
    unsigned int r;
    asm("v_cvt_pk_bf16_f32 %0, %1, %2" : "=v"(r) : "v"(lo), "v"(hi));
    return r;
}

// ---------------------------------------------------------------------------
// Merged prep: weight transposes [K x C] fp32 -> [C x 256] bf16, plus
// encoded fp32 -> bf16 conversion on z >= 104.
// ---------------------------------------------------------------------------
__global__ __launch_bounds__(256) void prep_all_kernel(
    const float* kW1, const float* vW1, const float* kW2, const float* vW2,
    const float* kW3, const float* vW3,
    const float* ds_W, const float* ff_W1, const float* ff_W2,
    const float* de_W1, const float* de_W2, const float* de_W3,
    const float* encoded,
    unsigned short* __restrict__ W1t, unsigned short* __restrict__ W2t,
    unsigned short* __restrict__ W3t, unsigned short* __restrict__ Wm,
    unsigned short* __restrict__ Xbf)
{
    const int z = blockIdx.z;
    if (z >= 104) {
        const int idx = (z - 104) * 64 + blockIdx.y * 8 + blockIdx.x;
        if (idx >= 4096) return;                 // 4096 * 256 float4 = full X
        const int i = idx * 256 + threadIdx.x;   // float4 index
        float4 v = ((const float4*)encoded)[i];
        ushort4 o;
        o.x = f2bf(v.x); o.y = f2bf(v.y); o.z = f2bf(v.z); o.w = f2bf(v.w);
        ((ushort4*)Xbf)[i] = o;
        return;
    }
    const float* src;
    unsigned short* dst;
    int C;
    if (z < 32) {
        const int net = z;
        src = ((net >> 4) ? vW1 : kW1) + (size_t)(net & 15) * 257 * 256;
        dst = W1t + (size_t)net * 65536;
        C = 256;
    } else if (z < 64) {
        const int net = z - 32;
        src = ((net >> 4) ? vW2 : kW2) + (size_t)(net & 15) * 256 * 256;
        dst = W2t + (size_t)net * 65536;
        C = 256;
    } else if (z < 96) {
        const int net = z - 64;
        src = ((net >> 4) ? vW3 : kW3) + (size_t)(net & 15) * 256 * 32;
        dst = W3t + (size_t)net * 8192;
        C = 32;
    } else {
        const int id = z - 96;
        const float* srcs[8] = {ds_W, ff_W1, ff_W1 + (size_t)65536,
                                ff_W2, ff_W2 + (size_t)65536, de_W1, de_W2, de_W3};
        src = srcs[id];
        dst = Wm + (size_t)id * 65536;
        C = (id == 7) ? 128 : 256;
    }
    if (blockIdx.x * 32 >= C) return;
    __shared__ float t[32][33];
    const int c0 = blockIdx.x * 32, k0 = blockIdx.y * 32;
    const int tx = threadIdx.x & 31, ty = threadIdx.x >> 5;
    #pragma unroll
    for (int i = 0; i < 32; i += 8)
        t[ty + i][tx] = src[(size_t)(k0 + ty + i) * C + (c0 + tx)];
    __syncthreads();
    #pragma unroll
    for (int i = 0; i < 32; i += 8)
        dst[(size_t)(c0 + ty + i) * 256 + (k0 + tx)] = f2bf(t[tx][ty + i]);
}

// h-buf XOR swizzle: rows x 256 shorts (32 chunks of 8 shorts).
static __device__ __forceinline__ int hsw_chunk(int row, int ks, int quad) {
    int c = ks * 4 + quad;
    int p = c ^ (row & 31);
    return row * 256 + p * 8;
}
static __device__ __forceinline__ int hsw_elem(int row, int col) {
    int p = (col >> 3) ^ (row & 31);
    return row * 256 + p * 8 + (col & 7);
}
// packed b64 write address (col0 multiple of 4) in shorts
static __device__ __forceinline__ int hsw_b64(int row, int col0) {
    int c = col0 >> 3;
    return row * 256 + ((c ^ (row & 31)) * 8) + (col0 & 7);
}

// ---------------------------------------------------------------------------
// Fused 3-layer KV MLP — v11s: v11 + s_setprio(1) around MFMA clusters
// (waves 0-3 carry S3 -> intra-span role diversity; T5 regime).
// ---------------------------------------------------------------------------
__global__ __launch_bounds__(512, 2) void kv_mfma_kernel(
    const unsigned short* __restrict__ Xbf, const float* __restrict__ true_u,
    const unsigned short* __restrict__ W1t, const unsigned short* __restrict__ W2t,
    const unsigned short* __restrict__ W3t,
    const float* __restrict__ kW1, const float* __restrict__ vW1,
    const float* __restrict__ kb1, const float* __restrict__ kb2, const float* __restrict__ kb3,
    const float* __restrict__ vb1, const float* __restrict__ vb2, const float* __restrict__ vb3,
    unsigned short* __restrict__ keys, unsigned short* __restrict__ vals)
{
    __shared__ unsigned short Xb[2][32 * 256];    // 2x16 KB: X tiles
    __shared__ unsigned short H1b[2][32 * 256];   // 2x16 KB: h1 tiles
    __shared__ unsigned short H2b[2][32 * 256];   // 2x16 KB: h2 tiles
    __shared__ unsigned short w3buf[32 * 256];    // 16 KB: W3 slice (swizzled)
    __shared__ float b1f[256], b2f[256], w1r[256];
    __shared__ float tua[2048];                   // all true_u rows of block

    const int tid = threadIdx.x;
    const int w = tid >> 6, lane = tid & 63;
    const int ln = lane & 15, quad = lane >> 4;
    const int lh = blockIdx.y, isv = blockIdx.z;
    const int net = isv * 16 + lh;
    const float* W1f = (isv ? vW1 : kW1) + (size_t)lh * 257 * 256;
    const float* b1  = (isv ? vb1 : kb1) + lh * 256;
    const float* b2  = (isv ? vb2 : kb2) + lh * 256;
    const float* b3  = (isv ? vb3 : kb3) + lh * 32;
    const unsigned short* w1 = W1t + (size_t)net * 65536;
    const unsigned short* w2 = W2t + (size_t)net * 65536;
    const unsigned short* w3 = W3t + (size_t)net * 8192;
    unsigned short* outp = isv ? vals : keys;
    const int base = blockIdx.x * 2048;          // row-group = one batch
    const int cb = w * 32;                       // wave's 32-col base (S1-S2)
    constexpr int NT = 64;                       // 32-row tiles per block

    // ---- one-time: W1/W2 column slices (32 cols/wave) -> registers ----
    bf16x8 B1[16], B2[16];
    {
        const unsigned short* p1 = w1 + (size_t)(cb + ln) * 256 + quad * 8;
        const unsigned short* p2 = w2 + (size_t)(cb + ln) * 256 + quad * 8;
        #pragma unroll
        for (int ks = 0; ks < 8; ++ks)
            #pragma unroll
            for (int ct = 0; ct < 2; ++ct) {
                B1[ks * 2 + ct] = *(const bf16x8*)(p1 + (size_t)ct * 16 * 256 + ks * 32);
                B2[ks * 2 + ct] = *(const bf16x8*)(p2 + (size_t)ct * 16 * 256 + ks * 32);
            }
    }
    // ---- one-time: W3 -> swizzled LDS (1024 chunks, 2/thread) ----
    {
        #pragma unroll
        for (int j = 0; j < 2; ++j) {
            const int cidx = tid * 2 + j;
            const int col = cidx >> 5, c = cidx & 31;
            uint4 d = *(const uint4*)(w3 + cidx * 8);
            *(uint4*)&w3buf[col * 256 + (c ^ (col & 31)) * 8] = d;
        }
    }
    // ---- one-time: biases / rank-1 row / true_u -> LDS ----
    if (tid < 256) {
        b1f[tid] = b1[tid];
        b2f[tid] = b2[tid];
        w1r[tid] = W1f[65536 + tid];
    }
    #pragma unroll
    for (int j = 0; j < 4; ++j)
        tua[tid + j * 512] = true_u[base + tid + j * 512];

    // S3 geometry (waves 0-3 active; masked-safe index calc for all)
    const int ww = w & 3, rt3 = ww & 1, ct3 = ww >> 1;
    const float4 b3v4 = *(const float4*)(b3 + ct3 * 16 + quad * 4);

    const int b_ = blockIdx.x;
    const int l_ = lh >> 3, h_ = lh & 7;
    unsigned short* ob = outp + (((size_t)l_ * Bc + b_) * Vc) * 256 + h_ * 32;

    const f32x4 zero = {0.f, 0.f, 0.f, 0.f};

    // ---- X staging via global_load_lds: 2 issues/wave, pre-swizzled src ----
    auto stage_x = [&](int rowbase, int buf) {
        #pragma unroll
        for (int j = 0; j < 2; ++j) {
            const int slot = w * 4 + j * 2;            // 2 rows per issue
            const int r = slot + (lane >> 5);          // tile row of this lane
            const int c = (lane & 31) ^ (r & 31);      // pre-swizzled src chunk
            const unsigned short* src = Xbf + (size_t)(rowbase + r) * 256 + c * 8;
            __builtin_amdgcn_global_load_lds(
                (const __attribute__((address_space(1))) void*)src,
                (__attribute__((address_space(3))) void*)&Xb[buf][slot * 256],
                16, 0, 0);
        }
    };

    // ---- prologue: stage X tile 0 ----
    stage_x(base, 0);
    __syncthreads();   // drains vmcnt -> X(0) visible; LDS consts visible

    for (int t = 0; t < NT + 2; ++t) {
        const bool d1 = (t < NT);
        const bool d2 = (t >= 1) && (t < NT + 1);
        const bool d3 = (t >= 2);

        // ---- prefetch X(t+1) (lands by span-end barrier) ----
        if (t + 1 < NT) stage_x(base + (t + 1) * 32, (t + 1) & 1);

        // ---- S1(t) MFMA: X[t&1] @ W1 ----
        f32x4 a1[2][2];
        if (d1) {
            #pragma unroll
            for (int rt = 0; rt < 2; ++rt) { a1[rt][0] = zero; a1[rt][1] = zero; }
            const unsigned short* Xc = Xb[t & 1];
            __builtin_amdgcn_s_setprio(1);
            #pragma unroll
            for (int ks = 0; ks < 8; ++ks) {
                bf16x8 A[2];
                #pragma unroll
                for (int rt = 0; rt < 2; ++rt)
                    A[rt] = *(const bf16x8*)&Xc[hsw_chunk(rt * 16 + ln, ks, quad)];
                #pragma unroll
                for (int rt = 0; rt < 2; ++rt)
                    #pragma unroll
                    for (int ct = 0; ct < 2; ++ct)
                        a1[rt][ct] = __builtin_amdgcn_mfma_f32_16x16x32_bf16(
                            B1[ks * 2 + ct], A[rt], a1[rt][ct], 0, 0, 0);
            }
            __builtin_amdgcn_s_setprio(0);
        }

        // ---- S2(t-1) MFMA: H1[(t-1)&1] @ W2 ----
        f32x4 a2[2][2];
        if (d2) {
            #pragma unroll
            for (int rt = 0; rt < 2; ++rt) { a2[rt][0] = zero; a2[rt][1] = zero; }
            const unsigned short* Hc = H1b[(t - 1) & 1];
            __builtin_amdgcn_s_setprio(1);
            #pragma unroll
            for (int ks = 0; ks < 8; ++ks) {
                bf16x8 A[2];
                #pragma unroll
                for (int rt = 0; rt < 2; ++rt)
                    A[rt] = *(const bf16x8*)&Hc[hsw_chunk(rt * 16 + ln, ks, quad)];
                #pragma unroll
                for (int rt = 0; rt < 2; ++rt)
                    #pragma unroll
                    for (int ct = 0; ct < 2; ++ct)
                        a2[rt][ct] = __builtin_amdgcn_mfma_f32_16x16x32_bf16(
                            B2[ks * 2 + ct], A[rt], a2[rt][ct], 0, 0, 0);
            }
            __builtin_amdgcn_s_setprio(0);
        }

        // ---- S1(t) epilogue -> H1[t&1] ----
        if (d1) {
            unsigned short* h1p = H1b[t & 1];
            #pragma unroll
            for (int rt = 0; rt < 2; ++rt) {
                const int row = rt * 16 + ln;
                const float tu = tua[t * 32 + row];
                #pragma unroll
                for (int ct = 0; ct < 2; ++ct) {
                    const int col0 = cb + ct * 16 + quad * 4;
                    const float4 bb = *(const float4*)&b1f[col0];
                    const float4 wr = *(const float4*)&w1r[col0];
                    const float v0 = fmaxf(a1[rt][ct][0] + bb.x + tu * wr.x, 0.f);
                    const float v1 = fmaxf(a1[rt][ct][1] + bb.y + tu * wr.y, 0.f);
                    const float v2 = fmaxf(a1[rt][ct][2] + bb.z + tu * wr.z, 0.f);
                    const float v3 = fmaxf(a1[rt][ct][3] + bb.w + tu * wr.w, 0.f);
                    uint2 o; o.x = cvt2(v0, v1); o.y = cvt2(v2, v3);
                    *(uint2*)&h1p[hsw_b64(row, col0)] = o;
                }
            }
        }

        // ---- S2(t-1) epilogue -> H2[(t-1)&1] ----
        if (d2) {
            unsigned short* h2p = H2b[(t - 1) & 1];
            #pragma unroll
            for (int rt = 0; rt < 2; ++rt) {
                const int row = rt * 16 + ln;
                #pragma unroll
                for (int ct = 0; ct < 2; ++ct) {
                    const int col0 = cb + ct * 16 + quad * 4;
                    const float4 bb = *(const float4*)&b2f[col0];
                    const float v0 = fmaxf(a2[rt][ct][0] + bb.x, 0.f);
                    const float v1 = fmaxf(a2[rt][ct][1] + bb.y, 0.f);
                    const float v2 = fmaxf(a2[rt][ct][2] + bb.z, 0.f);
                    const float v3 = fmaxf(a2[rt][ct][3] + bb.w, 0.f);
                    uint2 o; o.x = cvt2(v0, v1); o.y = cvt2(v2, v3);
                    *(uint2*)&h2p[hsw_b64(row, col0)] = o;
                }
            }
        }

        // ---- S3(t-2): H2[(t-2)&1] @ W3 -> global (waves 0-3) ----
        if (d3 && w < 4) {
            const int v = t - 2;
            const unsigned short* h2p = H2b[v & 1];
            f32x4 a3 = zero;
            __builtin_amdgcn_s_setprio(1);
            #pragma unroll
            for (int ks = 0; ks < 8; ++ks) {
                bf16x8 Aw = *(const bf16x8*)&w3buf[hsw_chunk(ct3 * 16 + ln, ks, quad)];
                bf16x8 Ah = *(const bf16x8*)&h2p[hsw_chunk(rt3 * 16 + ln, ks, quad)];
                a3 = __builtin_amdgcn_mfma_f32_16x16x32_bf16(Aw, Ah, a3, 0, 0, 0);
            }
            __builtin_amdgcn_s_setprio(0);
            const int grow = base + v * 32 + rt3 * 16 + ln;
            const float v0 = a3[0] + b3v4.x;
            const float v1 = a3[1] + b3v4.y;
            const float v2 = a3[2] + b3v4.z;
            const float v3 = a3[3] + b3v4.w;
            uint2 o; o.x = cvt2(v0, v1); o.y = cvt2(v2, v3);
            *(uint2*)(ob + (size_t)(grow & 2047) * 256 + ct3 * 16 + quad * 4) = o;
        }

        __syncthreads();   // span end: all LDS writes visible, X(t+1) landed
    }
}

// ---------------------------------------------------------------------------
// FUSED TAIL (v1 + K/V cross-head prefetch + no-max softmax): 16 rows/block,
// 512 threads, 256 blocks. K and V for head h+1 both prefetched during head
// h (full head of latency cover, ~600 cyc); no-max softmax (scores bounded
// by construction); __expf + v_rcp.
// ---------------------------------------------------------------------------
__global__ __launch_bounds__(512) void decoder_kernel(
    const unsigned short* __restrict__ Xbf, const float* __restrict__ true_u,
    const unsigned short* __restrict__ keys, const unsigned short* __restrict__ vals,
    const int* __restrict__ nbr, const float* __restrict__ mask,
    const int* __restrict__ pp, const unsigned short* __restrict__ Wm,
    const float* __restrict__ ds_b,
    const float* __restrict__ ln1_g, const float* __restrict__ ln1_b,
    const float* __restrict__ ff_b1, const float* __restrict__ ff_b2,
    const float* __restrict__ ln2_g, const float* __restrict__ ln2_b,
    const float* __restrict__ de_b1, const float* __restrict__ de_b2,
    const float* __restrict__ de_b3, float* __restrict__ outp)
{
    __shared__ float avF[16][264];
    __shared__ float attF[16][264];
    __shared__ unsigned short abuf[16 * 256];
    __shared__ unsigned short hbuf[16 * 256];
    __shared__ int   ni_s[16][64];
    __shared__ float wtsb[16][64];
    __shared__ float psum[16][8], psq[16][8];
    __shared__ float rowmax[16];
    __shared__ int   tcol[16];
    __shared__ int   pps[16];

    const int tid = threadIdx.x;
    const int w = tid >> 6, lane = tid & 63;
    const int ln = lane & 15, quad = lane >> 4;
    const int bid = blockIdx.x;
    const int b = bid & 7;                       // XCD-affine batch
    const int r0 = b * 512 + (bid >> 3) * 16;    // global row base
    const int cb = w * 32;                       // GEMM column base

    const f32x4 zero = {0.f, 0.f, 0.f, 0.f};

    // ---- init: pp values + neighbor indices ----
    if (tid < 16) pps[tid] = pp[(r0 + tid) & 511];
    #pragma unroll
    for (int j = 0; j < 2; ++j) {
        const int idx = tid * 2 + j;             // 1024 = 16*64
        const int row = idx >> 6, n = idx & 63;
        ni_s[row][n] = nbr[((r0 + row) & 511) * 64 + n];
    }
    __syncthreads();

    // ---- gather X rows into abuf ----
    {
        const int row = tid >> 5, c = tid & 31;
        const size_t arow = (size_t)b * Vc + pps[row];
        uint4 d = *(const uint4*)(Xbf + arow * 256 + c * 8);
        *(uint4*)&abuf[row * 256 + ((c ^ row) * 8)] = d;
    }
    __syncthreads();

    // ---- ds GEMM ----
    {
        const unsigned short* Wt = Wm;
        f32x4 acc[2]; acc[0] = zero; acc[1] = zero;
        const unsigned short* wb = Wt + (size_t)(cb + ln) * 256 + quad * 8;
        #pragma unroll
        for (int ks = 0; ks < 8; ++ks) {
            bf16x8 A = *(const bf16x8*)&abuf[hsw_chunk(ln, ks, quad)];
            #pragma unroll
            for (int ct = 0; ct < 2; ++ct) {
                bf16x8 Bv = *(const bf16x8*)(wb + (size_t)ct * 16 * 256 + ks * 32);
                acc[ct] = __builtin_amdgcn_mfma_f32_16x16x32_bf16(A, Bv, acc[ct], 0, 0, 0);
            }
        }
        __syncthreads();
        #pragma unroll
        for (int ct = 0; ct < 2; ++ct) {
            const int col = cb + ct * 16 + ln;
            const float bb = ds_b[col];
            #pragma unroll
            for (int r = 0; r < 4; ++r) {
                const int row = quad * 4 + r;
                float v = acc[ct][r] + bb;
                avF[row][col] = v;
                abuf[hsw_elem(row, col)] = f2bf(v);
            }
        }
    }
    __syncthreads();

    // ==================== transformer layers ====================
    for (int l = 0; l < Lc; ++l) {
        const unsigned short* kvb = keys + (((size_t)l * Bc + b) * Vc) * 256;
        const unsigned short* vvb = vals + (((size_t)l * Bc + b) * Vc) * 256;

        // ---- attention: rows w*2 and w*2+1 interleaved, K+V pipelined ----
        {
            const int row0a = w * 2, row1a = w * 2 + 1;
            const int p0 = (r0 + row0a) & 511, p1 = (r0 + row1a) & 511;
            const int n = lane;
            const int vi0 = ni_s[row0a][n], vi1 = ni_s[row1a][n];
            const float m0 = mask[p0 * 64 + n], m1 = mask[p1 * 64 + n];
            const int nb4 = n >> 2, cg8 = (n & 3) * 8;
            int vrow0[4], vrow1[4];
            #pragma unroll
            for (int pass = 0; pass < 4; ++pass) {
                const int nn = pass * 16 + nb4;
                vrow0[pass] = ni_s[row0a][nn];
                vrow1[pass] = ni_s[row1a][nn];
            }
            const unsigned short* kr0 = kvb + (size_t)vi0 * 256;
            const unsigned short* kr1 = kvb + (size_t)vi1 * 256;
            // K + V for head 0
            uint4 ku0[4], ku1[4], vu0[4], vu1[4];
            #pragma unroll
            for (int j = 0; j < 4; ++j) {
                ku0[j] = *(const uint4*)(kr0 + j * 8);
                ku1[j] = *(const uint4*)(kr1 + j * 8);
            }
            #pragma unroll
            for (int pass = 0; pass < 4; ++pass) {
                vu0[pass] = *(const uint4*)(vvb + (size_t)vrow0[pass] * 256 + cg8);
                vu1[pass] = *(const uint4*)(vvb + (size_t)vrow1[pass] * 256 + cg8);
            }
            for (int h = 0; h < 8; ++h) {
                // K+V prefetch for head h+1 (full head of latency cover)
                uint4 kn0[4], kn1[4], vn0[4], vn1[4];
                if (h < 7) {
                    #pragma unroll
                    for (int j = 0; j < 4; ++j) {
                        kn0[j] = *(const uint4*)(kr0 + (h + 1) * 32 + j * 8);
                        kn1[j] = *(const uint4*)(kr1 + (h + 1) * 32 + j * 8);
                    }
                    #pragma unroll
                    for (int pass = 0; pass < 4; ++pass) {
                        vn0[pass] = *(const uint4*)(vvb + (size_t)vrow0[pass] * 256 + (h + 1) * 32 + cg8);
                        vn1[pass] = *(const uint4*)(vvb + (size_t)vrow1[pass] * 256 + (h + 1) * 32 + cg8);
                    }
                }
                // q for both rows (broadcast LDS reads)
                float q0[32], q1[32];
                #pragma unroll
                for (int j = 0; j < 8; ++j) {
                    float4 t0 = *(const float4*)&avF[row0a][h * 32 + j * 4];
                    float4 t1 = *(const float4*)&avF[row1a][h * 32 + j * 4];
                    q0[j * 4 + 0] = t0.x; q0[j * 4 + 1] = t0.y;
                    q0[j * 4 + 2] = t0.z; q0[j * 4 + 3] = t0.w;
                    q1[j * 4 + 0] = t1.x; q1[j * 4 + 1] = t1.y;
                    q1[j * 4 + 2] = t1.z; q1[j * 4 + 3] = t1.w;
                }
                // two independent score chains from prefetched K
                float s0 = 0.f, s1 = 0.f;
                #pragma unroll
                for (int j = 0; j < 4; ++j) {
                    uint4 u0 = ku0[j];
                    uint4 u1 = ku1[j];
                    s0 += q0[j * 8 + 0] * bflo(u0.x) + q0[j * 8 + 1] * bfhi(u0.x);
                    s1 += q1[j * 8 + 0] * bflo(u1.x) + q1[j * 8 + 1] * bfhi(u1.x);
                    s0 += q0[j * 8 + 2] * bflo(u0.y) + q0[j * 8 + 3] * bfhi(u0.y);
                    s1 += q1[j * 8 + 2] * bflo(u1.y) + q1[j * 8 + 3] * bfhi(u1.y);
                    s0 += q0[j * 8 + 4] * bflo(u0.z) + q0[j * 8 + 5] * bfhi(u0.z);
                    s1 += q1[j * 8 + 4] * bflo(u1.z) + q1[j * 8 + 5] * bfhi(u1.z);
                    s0 += q0[j * 8 + 6] * bflo(u0.w) + q0[j * 8 + 7] * bfhi(u0.w);
                    s1 += q1[j * 8 + 6] * bflo(u1.w) + q1[j * 8 + 7] * bfhi(u1.w);
                }
                s0 = (s0 - m0) * 0.17677669529663689f;
                s1 = (s1 - m1) * 0.17677669529663689f;
                // no-max softmax: exp directly (bounded args), then normalize
                float e0 = __expf(s0), e1 = __expf(s1);
                float sum0 = e0, sum1 = e1;
                #pragma unroll
                for (int off = 32; off >= 1; off >>= 1) {
                    sum0 += __shfl_xor(sum0, off);
                    sum1 += __shfl_xor(sum1, off);
                }
                const float r0i = __builtin_amdgcn_rcpf(sum0);
                const float r1i = __builtin_amdgcn_rcpf(sum1);
                wtsb[row0a][n] = e0 * r0i;
                wtsb[row1a][n] = e1 * r1i;
                // PV with preloaded V
                float a0[8], a1[8];
                #pragma unroll
                for (int j = 0; j < 8; ++j) { a0[j] = 0.f; a1[j] = 0.f; }
                #pragma unroll
                for (int pass = 0; pass < 4; ++pass) {
                    const int nn = pass * 16 + nb4;
                    const float w0 = wtsb[row0a][nn], w1 = wtsb[row1a][nn];
                    uint4 u0 = vu0[pass];
                    uint4 u1 = vu1[pass];
                    a0[0] += w0 * bflo(u0.x); a0[1] += w0 * bfhi(u0.x);
                    a1[0] += w1 * bflo(u1.x); a1[1] += w1 * bfhi(u1.x);
                    a0[2] += w0 * bflo(u0.y); a0[3] += w0 * bfhi(u0.y);
                    a1[2] += w1 * bflo(u1.y); a1[3] += w1 * bfhi(u1.y);
                    a0[4] += w0 * bflo(u0.z); a0[5] += w0 * bfhi(u0.z);
                    a1[4] += w1 * bflo(u1.z); a1[5] += w1 * bfhi(u1.z);
                    a0[6] += w0 * bflo(u0.w); a0[7] += w0 * bfhi(u0.w);
                    a1[6] += w1 * bflo(u1.w); a1[7] += w1 * bfhi(u1.w);
                }
                #pragma unroll
                for (int off = 4; off <= 32; off <<= 1)
                    #pragma unroll
                    for (int j = 0; j < 8; ++j) {
                        a0[j] += __shfl_xor(a0[j], off);
                        a1[j] += __shfl_xor(a1[j], off);
                    }
                if (nb4 == 0)
                    #pragma unroll
                    for (int j = 0; j < 8; ++j) {
                        attF[row0a][h * 32 + cg8 + j] = a0[j];
                        attF[row1a][h * 32 + cg8 + j] = a1[j];
                    }
                // rotate prefetched K/V into place
                if (h < 7) {
                    #pragma unroll
                    for (int j = 0; j < 4; ++j) {
                        ku0[j] = kn0[j]; ku1[j] = kn1[j];
                        vu0[j] = vn0[j]; vu1[j] = vn1[j];
                    }
                }
            }
            // LN1 for both rows (in-wave)
            #pragma unroll
            for (int rr = 0; rr < 2; ++rr) {
                const int row = w * 2 + rr;
                const int c0 = lane * 4;
                float x[4];
                float sl = 0.f, ql = 0.f;
                #pragma unroll
                for (int j = 0; j < 4; ++j) {
                    x[j] = avF[row][c0 + j] + attF[row][c0 + j];
                    sl += x[j]; ql += x[j] * x[j];
                }
                #pragma unroll
                for (int off = 32; off >= 1; off >>= 1) {
                    sl += __shfl_xor(sl, off);
                    ql += __shfl_xor(ql, off);
                }
                const float mu = sl * (1.0f / 256.0f);
                const float var = ql * (1.0f / 256.0f) - mu * mu;
                const float rstd = 1.0f / sqrtf(fmaxf(var, 0.f) + 1e-5f);
                #pragma unroll
                for (int j = 0; j < 4; ++j) {
                    const int col = c0 + j;
                    float o = (x[j] - mu) * rstd * ln1_g[l * 256 + col] + ln1_b[l * 256 + col];
                    avF[row][col] = o;
                    abuf[hsw_elem(row, col)] = f2bf(o);
                }
            }
        }
        __syncthreads();

        // ---- ff stage A: T1 = relu(abuf @ W1 + b1) -> hbuf ----
        {
            const unsigned short* W1 = Wm + (size_t)(1 + l) * 65536;
            f32x4 acc[2]; acc[0] = zero; acc[1] = zero;
            const unsigned short* wb = W1 + (size_t)(cb + ln) * 256 + quad * 8;
            #pragma unroll
            for (int ks = 0; ks < 8; ++ks) {
                bf16x8 A = *(const bf16x8*)&abuf[hsw_chunk(ln, ks, quad)];
                #pragma unroll
                for (int ct = 0; ct < 2; ++ct) {
                    bf16x8 Bv = *(const bf16x8*)(wb + (size_t)ct * 16 * 256 + ks * 32);
                    acc[ct] = __builtin_amdgcn_mfma_f32_16x16x32_bf16(A, Bv, acc[ct], 0, 0, 0);
                }
            }
            #pragma unroll
            for (int ct = 0; ct < 2; ++ct) {
                const int col = cb + ct * 16 + ln;
                const float bb = ff_b1[l * 256 + col];
                #pragma unroll
                for (int r = 0; r < 4; ++r) {
                    const int row = quad * 4 + r;
                    hbuf[hsw_elem(row, col)] = f2bf(fmaxf(acc[ct][r] + bb, 0.f));
                }
            }
        }
        __syncthreads();

        // ---- ff stage B + residual + LN2 ----
        {
            const unsigned short* W2 = Wm + (size_t)(3 + l) * 65536;
            f32x4 acc[2]; acc[0] = zero; acc[1] = zero;
            const unsigned short* wb = W2 + (size_t)(cb + ln) * 256 + quad * 8;
            #pragma unroll
            for (int ks = 0; ks < 8; ++ks) {
                bf16x8 A = *(const bf16x8*)&hbuf[hsw_chunk(ln, ks, quad)];
                #pragma unroll
                for (int ct = 0; ct < 2; ++ct) {
                    bf16x8 Bv = *(const bf16x8*)(wb + (size_t)ct * 16 * 256 + ks * 32);
                    acc[ct] = __builtin_amdgcn_mfma_f32_16x16x32_bf16(A, Bv, acc[ct], 0, 0, 0);
                }
            }
            float vv[2][4];
            #pragma unroll
            for (int ct = 0; ct < 2; ++ct) {
                const int col = cb + ct * 16 + ln;
                const float bb = ff_b2[l * 256 + col];
                #pragma unroll
                for (int r = 0; r < 4; ++r) {
                    const int row = quad * 4 + r;
                    vv[ct][r] = acc[ct][r] + bb + avF[row][col];
                }
            }
            #pragma unroll
            for (int r = 0; r < 4; ++r) {
                float sl = vv[0][r] + vv[1][r];
                float ql = vv[0][r] * vv[0][r] + vv[1][r] * vv[1][r];
                #pragma unroll
                for (int off = 8; off >= 1; off >>= 1) {
                    sl += __shfl_xor(sl, off);
                    ql += __shfl_xor(ql, off);
                }
                if (ln == 0) {
                    const int row = quad * 4 + r;
                    psum[row][w] = sl; psq[row][w] = ql;
                }
            }
            __syncthreads();
            #pragma unroll
            for (int r = 0; r < 4; ++r) {
                const int row = quad * 4 + r;
                float sl = 0.f, ql = 0.f;
                #pragma unroll
                for (int j = 0; j < 8; ++j) { sl += psum[row][j]; ql += psq[row][j]; }
                const float mu = sl * (1.0f / 256.0f);
                const float var = ql * (1.0f / 256.0f) - mu * mu;
                const float rstd = 1.0f / sqrtf(fmaxf(var, 0.f) + 1e-5f);
                #pragma unroll
                for (int ct = 0; ct < 2; ++ct) {
                    const int col = cb + ct * 16 + ln;
                    float o = (vv[ct][r] - mu) * rstd * ln2_g[l * 256 + col] + ln2_b[l * 256 + col];
                    avF[row][col] = o;
                    abuf[hsw_elem(row, col)] = f2bf(o);
                }
            }
        }
        __syncthreads();
    }

    // ==================== decoder + loss ====================
    {
        const unsigned short* W1 = Wm + (size_t)5 * 65536;
        f32x4 acc[2]; acc[0] = zero; acc[1] = zero;
        const unsigned short* wb = W1 + (size_t)(cb + ln) * 256 + quad * 8;
        #pragma unroll
        for (int ks = 0; ks < 8; ++ks) {
            bf16x8 A = *(const bf16x8*)&abuf[hsw_chunk(ln, ks, quad)];
            #pragma unroll
            for (int ct = 0; ct < 2; ++ct) {
                bf16x8 Bv = *(const bf16x8*)(wb + (size_t)ct * 16 * 256 + ks * 32);
                acc[ct] = __builtin_amdgcn_mfma_f32_16x16x32_bf16(A, Bv, acc[ct], 0, 0, 0);
            }
        }
        #pragma unroll
        for (int ct = 0; ct < 2; ++ct) {
            const int col = cb + ct * 16 + ln;
            const float bb = de_b1[col];
            #pragma unroll
            for (int r = 0; r < 4; ++r) {
                const int row = quad * 4 + r;
                hbuf[hsw_elem(row, col)] = f2bf(fmaxf(acc[ct][r] + bb, 0.f));
            }
        }
    }
    __syncthreads();

    {
        const unsigned short* W2 = Wm + (size_t)6 * 65536;
        f32x4 acc[2]; acc[0] = zero; acc[1] = zero;
        const unsigned short* wb = W2 + (size_t)(cb + ln) * 256 + quad * 8;
        #pragma unroll
        for (int ks = 0; ks < 8; ++ks) {
            bf16x8 A = *(const bf16x8*)&hbuf[hsw_chunk(ln, ks, quad)];
            #pragma unroll
            for (int ct = 0; ct < 2; ++ct) {
                bf16x8 Bv = *(const bf16x8*)(wb + (size_t)ct * 16 * 256 + ks * 32);
                acc[ct] = __builtin_amdgcn_mfma_f32_16x16x32_bf16(A, Bv, acc[ct], 0, 0, 0);
            }
        }
        __syncthreads();
        #pragma unroll
        for (int ct = 0; ct < 2; ++ct) {
            const int col = cb + ct * 16 + ln;
            const float bb = de_b2[col];
            #pragma unroll
            for (int r = 0; r < 4; ++r) {
                const int row = quad * 4 + r;
                hbuf[hsw_elem(row, col)] = f2bf(fmaxf(acc[ct][r] + bb, 0.f));
            }
        }
    }
    __syncthreads();

    {
        const unsigned short* W3 = Wm + (size_t)7 * 65536;
        const int cb3 = w * 16;
        f32x4 a3 = zero;
        const unsigned short* wb = W3 + (size_t)(cb3 + ln) * 256 + quad * 8;
        #pragma unroll
        for (int ks = 0; ks < 8; ++ks) {
            bf16x8 A = *(const bf16x8*)&hbuf[hsw_chunk(ln, ks, quad)];
            bf16x8 Bv = *(const bf16x8*)(wb + ks * 32);
            a3 = __builtin_amdgcn_mfma_f32_16x16x32_bf16(A, Bv, a3, 0, 0, 0);
        }
        float lg[4];
        const float bb = de_b3[cb3 + ln];
        #pragma unroll
        for (int r = 0; r < 4; ++r) lg[r] = a3[r] + bb;

        #pragma unroll
        for (int r = 0; r < 4; ++r) {
            float m = lg[r];
            #pragma unroll
            for (int off = 8; off >= 1; off >>= 1) m = fmaxf(m, __shfl_xor(m, off));
            if (ln == 0) psum[quad * 4 + r][w] = m;
        }
        __syncthreads();
        if (tid < 16) {
            float m = psum[tid][0];
            #pragma unroll
            for (int j = 1; j < 8; ++j) m = fmaxf(m, psum[tid][j]);
            rowmax[tid] = m;
            float tu = true_u[(size_t)b * Vc + pps[tid]];
            int t = (int)floorf(tu * 128.0f);
            tcol[tid] = t < 0 ? 0 : (t > 127 ? 127 : t);
        }
        __syncthreads();
        #pragma unroll
        for (int r = 0; r < 4; ++r) {
            const int row = quad * 4 + r;
            const float mx = rowmax[row];
            const int t = tcol[row];
            float e = expf(lg[r] - mx);
            float xt = ((cb3 + ln) == t) ? lg[r] : 0.f;
            #pragma unroll
            for (int off = 8; off >= 1; off >>= 1) {
                e += __shfl_xor(e, off);
                xt += __shfl_xor(xt, off);
            }
            if (ln == 0) { psum[row][w] = e; psq[row][w] = xt; }
        }
        __syncthreads();
        float contrib = 0.f;
        if (tid < 16) {
            float sum = 0.f, xt = 0.f;
            #pragma unroll
            for (int j = 0; j < 8; ++j) { sum += psum[tid][j]; xt += psq[tid][j]; }
            const float lp = logf(128.0f) + (xt - rowmax[tid]) - logf(sum);
            contrib = -lp;
        }
        if (w == 0) {
            #pragma unroll
            for (int off = 32; off >= 1; off >>= 1) contrib += __shfl_xor(contrib, off);
            if (lane == 0) atomicAdd(&outp[b], contrib);
        }
    }
}

// ---------------------------------------------------------------------------
extern "C" void kernel_launch(void* const* d_in, const int* in_sizes, int n_in,
                              void* d_out, int out_size, void* d_ws, size_t ws_size,
                              hipStream_t stream)
{
    (void)in_sizes; (void)n_in; (void)out_size; (void)ws_size;

    const float* encoded        = (const float*)d_in[0];
    const float* true_u         = (const float*)d_in[1];
    const float* attn_mask      = (const float*)d_in[2];
    const int*   pred_points    = (const int*)d_in[3];
    const int*   neighbor_index = (const int*)d_in[4];
    const float* kW1 = (const float*)d_in[5];
    const float* kb1 = (const float*)d_in[6];
    const float* kW2 = (const float*)d_in[7];
    const float* kb2 = (const float*)d_in[8];
    const float* kW3 = (const float*)d_in[9];
    const float* kb3 = (const float*)d_in[10];
    const float* vW1 = (const float*)d_in[11];
    const float* vb1 = (const float*)d_in[12];
    const float* vW2 = (const float*)d_in[13];
    const float* vb2 = (const float*)d_in[14];
    const float* vW3 = (const float*)d_in[15];
    const float* vb3 = (const float*)d_in[16];
    const float* ds_W  = (const float*)d_in[17];
    const float* ds_b  = (const float*)d_in[18];
    const float* ln1_g = (const float*)d_in[19];
    const float* ln1_b = (const float*)d_in[20];
    const float* ff_W1 = (const float*)d_in[21];
    const float* ff_b1 = (const float*)d_in[22];
    const float* ff_W2 = (const float*)d_in[23];
    const float* ff_b2 = (const float*)d_in[24];
    const float* ln2_g = (const float*)d_in[25];
    const float* ln2_b = (const float*)d_in[26];
    const float* de_W1 = (const float*)d_in[27];
    const float* de_b1 = (const float*)d_in[28];
    const float* de_W2 = (const float*)d_in[29];
    const float* de_b2 = (const float*)d_in[30];
    const float* de_W3 = (const float*)d_in[31];
    const float* de_b3 = (const float*)d_in[32];

    float* out = (float*)d_out;

    // workspace layout
    constexpr size_t KV_ELEMS = (size_t)Lc * Bc * Hc * Vc * 32;  // 8,388,608
    unsigned short* keys = (unsigned short*)d_ws;            // bf16 [l][b][v][256]
    unsigned short* vals = keys + KV_ELEMS;
    unsigned short* Xbf  = vals + KV_ELEMS;                  // 16384 x 256 bf16
    unsigned short* W1t  = Xbf + (size_t)ROWS_KV * 256;      // 32 nets x [256][256]
    unsigned short* W2t  = W1t + (size_t)32 * 65536;
    unsigned short* W3t  = W2t + (size_t)32 * 65536;         // 32 nets x [32][256]
    unsigned short* Wm   = W3t + (size_t)32 * 8192;          // 8 slots x 65536

    (void)hipMemsetAsync(out, 0, Bc * sizeof(float), stream);

    // prep (single launch: transposes + X conversion; 64 conv slices)
    prep_all_kernel<<<dim3(8, 8, 168), 256, 0, stream>>>(
        kW1, vW1, kW2, vW2, kW3, vW3,
        ds_W, ff_W1, ff_W2, de_W1, de_W2, de_W3, encoded,
        W1t, W2t, W3t, Wm, Xbf);

    // KV MLPs v11s: 8 rg x 16 (l,h) x {k,v} = 256 blocks, 512 thr, 1/CU
    kv_mfma_kernel<<<dim3(8, 16, 2), 512, 0, stream>>>(
        Xbf, true_u, W1t, W2t, W3t, kW1, vW1,
        kb1, kb2, kb3, vb1, vb2, vb3, keys, vals);

    // fused tail: K/V cross-head prefetch + no-max softmax
    decoder_kernel<<<dim3(ROWS_AT / 16), 512, 0, stream>>>(
        Xbf, true_u, keys, vals, neighbor_index, attn_mask, pred_points, Wm,
        ds_b, ln1_g, ln1_b, ff_b1, ff_b2, ln2_g, ln2_b,
        de_b1, de_b2, de_b3, out);
}

// Round 12
// 384.385 us; speedup vs baseline: 1.0179x; 1.0179x over previous
//
#include <hip/hip_runtime.h>
#include <hip/hip_bf16.h>
#include <cstdint>
#include <cstddef>

// Problem dims (compile-time)
constexpr int Bc = 8;
constexpr int Vc = 2048;   // S*T
constexpr int Pc = 512;
constexpr int Hc = 8;
constexpr int Lc = 2;
constexpr int ROWS_KV = Bc * Vc;   // 16384
constexpr int ROWS_AT = Bc * Pc;   // 4096

typedef __attribute__((ext_vector_type(8))) short bf16x8;   // 8 bf16 (4 VGPRs)
typedef __attribute__((ext_vector_type(4))) float f32x4;

static __device__ __forceinline__ unsigned short f2bf(float v) {
    __hip_bfloat16 h = __float2bfloat16(v);
    return *(unsigned short*)&h;
}
static __device__ __forceinline__ float bflo(unsigned int u) {
    return __uint_as_float(u << 16);
}
static __device__ __forceinline__ float bfhi(unsigned int u) {
    return __uint_as_float(u & 0xffff0000u);
}
// HW packed f32->bf16 (RNE), 1 inst per 2 elems
static __device__ __forceinline__ unsigned int cvt2(float lo, float hi) {
    unsigned int r;
    asm("v_cvt_pk_bf16_f32 %0, %1, %2" : "=v"(r) : "v"(lo), "v"(hi));
    return r;
}

// ---------------------------------------------------------------------------
// Merged prep: weight transposes [K x C] fp32 -> [C x 256] bf16, plus
// encoded fp32 -> bf16 conversion on z >= 104.
// ---------------------------------------------------------------------------
__global__ __launch_bounds__(256) void prep_all_kernel(
    const float* kW1, const float* vW1, const float* kW2, const float* vW2,
    const float* kW3, const float* vW3,
    const float* ds_W, const float* ff_W1, const float* ff_W2,
    const float* de_W1, const float* de_W2, const float* de_W3,
    const float* encoded,
    unsigned short* __restrict__ W1t, unsigned short* __restrict__ W2t,
    unsigned short* __restrict__ W3t, unsigned short* __restrict__ Wm,
    unsigned short* __restrict__ Xbf)
{
    const int z = blockIdx.z;
    if (z >= 104) {
        const int idx = (z - 104) * 64 + blockIdx.y * 8 + blockIdx.x;
        if (idx >= 4096) return;                 // 4096 * 256 float4 = full X
        const int i = idx * 256 + threadIdx.x;   // float4 index
        float4 v = ((const float4*)encoded)[i];
        ushort4 o;
        o.x = f2bf(v.x); o.y = f2bf(v.y); o.z = f2bf(v.z); o.w = f2bf(v.w);
        ((ushort4*)Xbf)[i] = o;
        return;
    }
    const float* src;
    unsigned short* dst;
    int C;
    if (z < 32) {
        const int net = z;
        src = ((net >> 4) ? vW1 : kW1) + (size_t)(net & 15) * 257 * 256;
        dst = W1t + (size_t)net * 65536;
        C = 256;
    } else if (z < 64) {
        const int net = z - 32;
        src = ((net >> 4) ? vW2 : kW2) + (size_t)(net & 15) * 256 * 256;
        dst = W2t + (size_t)net * 65536;
        C = 256;
    } else if (z < 96) {
        const int net = z - 64;
        src = ((net >> 4) ? vW3 : kW3) + (size_t)(net & 15) * 256 * 32;
        dst = W3t + (size_t)net * 8192;
        C = 32;
    } else {
        const int id = z - 96;
        const float* srcs[8] = {ds_W, ff_W1, ff_W1 + (size_t)65536,
                                ff_W2, ff_W2 + (size_t)65536, de_W1, de_W2, de_W3};
        src = srcs[id];
        dst = Wm + (size_t)id * 65536;
        C = (id == 7) ? 128 : 256;
    }
    if (blockIdx.x * 32 >= C) return;
    __shared__ float t[32][33];
    const int c0 = blockIdx.x * 32, k0 = blockIdx.y * 32;
    const int tx = threadIdx.x & 31, ty = threadIdx.x >> 5;
    #pragma unroll
    for (int i = 0; i < 32; i += 8)
        t[ty + i][tx] = src[(size_t)(k0 + ty + i) * C + (c0 + tx)];
    __syncthreads();
    #pragma unroll
    for (int i = 0; i < 32; i += 8)
        dst[(size_t)(c0 + ty + i) * 256 + (k0 + tx)] = f2bf(t[tx][ty + i]);
}

// h-buf XOR swizzle: rows x 256 shorts (32 chunks of 8 shorts).
static __device__ __forceinline__ int hsw_chunk(int row, int ks, int quad) {
    int c = ks * 4 + quad;
    int p = c ^ (row & 31);
    return row * 256 + p * 8;
}
static __device__ __forceinline__ int hsw_elem(int row, int col) {
    int p = (col >> 3) ^ (row & 31);
    return row * 256 + p * 8 + (col & 7);
}
// packed b64 write address (col0 multiple of 4) in shorts
static __device__ __forceinline__ int hsw_b64(int row, int col0) {
    int c = col0 >> 3;
    return row * 256 + ((c ^ (row & 31)) * 8) + (col0 & 7);
}

// ---------------------------------------------------------------------------
// Fused 3-layer KV MLP — v11 (known-good, 175 us): cross-tile stage
// pipeline, ONE barrier/span. 32-row tiles; span t runs S1(t) + S2(t-1) +
// S3(t-2) + both epilogues + X(t+1) global_load_lds prefetch as independent
// dataflow in one barrier span. 8 waves x 32 cols (B1[16]+B2[16]=128 VGPR)
// -> 2 waves/SIMD. Parity double-buffers (X/H1/H2). S3 on waves 0-3.
// NOTE: no setprio — measured −2 us without it (R11 A/B).
// ---------------------------------------------------------------------------
__global__ __launch_bounds__(512, 2) void kv_mfma_kernel(
    const unsigned short* __restrict__ Xbf, const float* __restrict__ true_u,
    const unsigned short* __restrict__ W1t, const unsigned short* __restrict__ W2t,
    const unsigned short* __restrict__ W3t,
    const float* __restrict__ kW1, const float* __restrict__ vW1,
    const float* __restrict__ kb1, const float* __restrict__ kb2, const float* __restrict__ kb3,
    const float* __restrict__ vb1, const float* __restrict__ vb2, const float* __restrict__ vb3,
    unsigned short* __restrict__ keys, unsigned short* __restrict__ vals)
{
    __shared__ unsigned short Xb[2][32 * 256];    // 2x16 KB: X tiles
    __shared__ unsigned short H1b[2][32 * 256];   // 2x16 KB: h1 tiles
    __shared__ unsigned short H2b[2][32 * 256];   // 2x16 KB: h2 tiles
    __shared__ unsigned short w3buf[32 * 256];    // 16 KB: W3 slice (swizzled)
    __shared__ float b1f[256], b2f[256], w1r[256];
    __shared__ float tua[2048];                   // all true_u rows of block

    const int tid = threadIdx.x;
    const int w = tid >> 6, lane = tid & 63;
    const int ln = lane & 15, quad = lane >> 4;
    const int lh = blockIdx.y, isv = blockIdx.z;
    const int net = isv * 16 + lh;
    const float* W1f = (isv ? vW1 : kW1) + (size_t)lh * 257 * 256;
    const float* b1  = (isv ? vb1 : kb1) + lh * 256;
    const float* b2  = (isv ? vb2 : kb2) + lh * 256;
    const float* b3  = (isv ? vb3 : kb3) + lh * 32;
    const unsigned short* w1 = W1t + (size_t)net * 65536;
    const unsigned short* w2 = W2t + (size_t)net * 65536;
    const unsigned short* w3 = W3t + (size_t)net * 8192;
    unsigned short* outp = isv ? vals : keys;
    const int base = blockIdx.x * 2048;          // row-group = one batch
    const int cb = w * 32;                       // wave's 32-col base (S1-S2)
    constexpr int NT = 64;                       // 32-row tiles per block

    // ---- one-time: W1/W2 column slices (32 cols/wave) -> registers ----
    bf16x8 B1[16], B2[16];
    {
        const unsigned short* p1 = w1 + (size_t)(cb + ln) * 256 + quad * 8;
        const unsigned short* p2 = w2 + (size_t)(cb + ln) * 256 + quad * 8;
        #pragma unroll
        for (int ks = 0; ks < 8; ++ks)
            #pragma unroll
            for (int ct = 0; ct < 2; ++ct) {
                B1[ks * 2 + ct] = *(const bf16x8*)(p1 + (size_t)ct * 16 * 256 + ks * 32);
                B2[ks * 2 + ct] = *(const bf16x8*)(p2 + (size_t)ct * 16 * 256 + ks * 32);
            }
    }
    // ---- one-time: W3 -> swizzled LDS (1024 chunks, 2/thread) ----
    {
        #pragma unroll
        for (int j = 0; j < 2; ++j) {
            const int cidx = tid * 2 + j;
            const int col = cidx >> 5, c = cidx & 31;
            uint4 d = *(const uint4*)(w3 + cidx * 8);
            *(uint4*)&w3buf[col * 256 + (c ^ (col & 31)) * 8] = d;
        }
    }
    // ---- one-time: biases / rank-1 row / true_u -> LDS ----
    if (tid < 256) {
        b1f[tid] = b1[tid];
        b2f[tid] = b2[tid];
        w1r[tid] = W1f[65536 + tid];
    }
    #pragma unroll
    for (int j = 0; j < 4; ++j)
        tua[tid + j * 512] = true_u[base + tid + j * 512];

    // S3 geometry (waves 0-3 active; masked-safe index calc for all)
    const int ww = w & 3, rt3 = ww & 1, ct3 = ww >> 1;
    const float4 b3v4 = *(const float4*)(b3 + ct3 * 16 + quad * 4);

    const int b_ = blockIdx.x;
    const int l_ = lh >> 3, h_ = lh & 7;
    unsigned short* ob = outp + (((size_t)l_ * Bc + b_) * Vc) * 256 + h_ * 32;

    const f32x4 zero = {0.f, 0.f, 0.f, 0.f};

    // ---- X staging via global_load_lds: 2 issues/wave, pre-swizzled src ----
    auto stage_x = [&](int rowbase, int buf) {
        #pragma unroll
        for (int j = 0; j < 2; ++j) {
            const int slot = w * 4 + j * 2;            // 2 rows per issue
            const int r = slot + (lane >> 5);          // tile row of this lane
            const int c = (lane & 31) ^ (r & 31);      // pre-swizzled src chunk
            const unsigned short* src = Xbf + (size_t)(rowbase + r) * 256 + c * 8;
            __builtin_amdgcn_global_load_lds(
                (const __attribute__((address_space(1))) void*)src,
                (__attribute__((address_space(3))) void*)&Xb[buf][slot * 256],
                16, 0, 0);
        }
    };

    // ---- prologue: stage X tile 0 ----
    stage_x(base, 0);
    __syncthreads();   // drains vmcnt -> X(0) visible; LDS consts visible

    for (int t = 0; t < NT + 2; ++t) {
        const bool d1 = (t < NT);
        const bool d2 = (t >= 1) && (t < NT + 1);
        const bool d3 = (t >= 2);

        // ---- prefetch X(t+1) (lands by span-end barrier) ----
        if (t + 1 < NT) stage_x(base + (t + 1) * 32, (t + 1) & 1);

        // ---- S1(t) MFMA: X[t&1] @ W1 ----
        f32x4 a1[2][2];
        if (d1) {
            #pragma unroll
            for (int rt = 0; rt < 2; ++rt) { a1[rt][0] = zero; a1[rt][1] = zero; }
            const unsigned short* Xc = Xb[t & 1];
            #pragma unroll
            for (int ks = 0; ks < 8; ++ks) {
                bf16x8 A[2];
                #pragma unroll
                for (int rt = 0; rt < 2; ++rt)
                    A[rt] = *(const bf16x8*)&Xc[hsw_chunk(rt * 16 + ln, ks, quad)];
                #pragma unroll
                for (int rt = 0; rt < 2; ++rt)
                    #pragma unroll
                    for (int ct = 0; ct < 2; ++ct)
                        a1[rt][ct] = __builtin_amdgcn_mfma_f32_16x16x32_bf16(
                            B1[ks * 2 + ct], A[rt], a1[rt][ct], 0, 0, 0);
            }
        }

        // ---- S2(t-1) MFMA: H1[(t-1)&1] @ W2 ----
        f32x4 a2[2][2];
        if (d2) {
            #pragma unroll
            for (int rt = 0; rt < 2; ++rt) { a2[rt][0] = zero; a2[rt][1] = zero; }
            const unsigned short* Hc = H1b[(t - 1) & 1];
            #pragma unroll
            for (int ks = 0; ks < 8; ++ks) {
                bf16x8 A[2];
                #pragma unroll
                for (int rt = 0; rt < 2; ++rt)
                    A[rt] = *(const bf16x8*)&Hc[hsw_chunk(rt * 16 + ln, ks, quad)];
                #pragma unroll
                for (int rt = 0; rt < 2; ++rt)
                    #pragma unroll
                    for (int ct = 0; ct < 2; ++ct)
                        a2[rt][ct] = __builtin_amdgcn_mfma_f32_16x16x32_bf16(
                            B2[ks * 2 + ct], A[rt], a2[rt][ct], 0, 0, 0);
            }
        }

        // ---- S1(t) epilogue -> H1[t&1] ----
        if (d1) {
            unsigned short* h1p = H1b[t & 1];
            #pragma unroll
            for (int rt = 0; rt < 2; ++rt) {
                const int row = rt * 16 + ln;
                const float tu = tua[t * 32 + row];
                #pragma unroll
                for (int ct = 0; ct < 2; ++ct) {
                    const int col0 = cb + ct * 16 + quad * 4;
                    const float4 bb = *(const float4*)&b1f[col0];
                    const float4 wr = *(const float4*)&w1r[col0];
                    const float v0 = fmaxf(a1[rt][ct][0] + bb.x + tu * wr.x, 0.f);
                    const float v1 = fmaxf(a1[rt][ct][1] + bb.y + tu * wr.y, 0.f);
                    const float v2 = fmaxf(a1[rt][ct][2] + bb.z + tu * wr.z, 0.f);
                    const float v3 = fmaxf(a1[rt][ct][3] + bb.w + tu * wr.w, 0.f);
                    uint2 o; o.x = cvt2(v0, v1); o.y = cvt2(v2, v3);
                    *(uint2*)&h1p[hsw_b64(row, col0)] = o;
                }
            }
        }

        // ---- S2(t-1) epilogue -> H2[(t-1)&1] ----
        if (d2) {
            unsigned short* h2p = H2b[(t - 1) & 1];
            #pragma unroll
            for (int rt = 0; rt < 2; ++rt) {
                const int row = rt * 16 + ln;
                #pragma unroll
                for (int ct = 0; ct < 2; ++ct) {
                    const int col0 = cb + ct * 16 + quad * 4;
                    const float4 bb = *(const float4*)&b2f[col0];
                    const float v0 = fmaxf(a2[rt][ct][0] + bb.x, 0.f);
                    const float v1 = fmaxf(a2[rt][ct][1] + bb.y, 0.f);
                    const float v2 = fmaxf(a2[rt][ct][2] + bb.z, 0.f);
                    const float v3 = fmaxf(a2[rt][ct][3] + bb.w, 0.f);
                    uint2 o; o.x = cvt2(v0, v1); o.y = cvt2(v2, v3);
                    *(uint2*)&h2p[hsw_b64(row, col0)] = o;
                }
            }
        }

        // ---- S3(t-2): H2[(t-2)&1] @ W3 -> global (waves 0-3) ----
        if (d3 && w < 4) {
            const int v = t - 2;
            const unsigned short* h2p = H2b[v & 1];
            f32x4 a3 = zero;
            #pragma unroll
            for (int ks = 0; ks < 8; ++ks) {
                bf16x8 Aw = *(const bf16x8*)&w3buf[hsw_chunk(ct3 * 16 + ln, ks, quad)];
                bf16x8 Ah = *(const bf16x8*)&h2p[hsw_chunk(rt3 * 16 + ln, ks, quad)];
                a3 = __builtin_amdgcn_mfma_f32_16x16x32_bf16(Aw, Ah, a3, 0, 0, 0);
            }
            const int grow = base + v * 32 + rt3 * 16 + ln;
            const float v0 = a3[0] + b3v4.x;
            const float v1 = a3[1] + b3v4.y;
            const float v2 = a3[2] + b3v4.z;
            const float v3 = a3[3] + b3v4.w;
            uint2 o; o.x = cvt2(v0, v1); o.y = cvt2(v2, v3);
            *(uint2*)(ob + (size_t)(grow & 2047) * 256 + ct3 * 16 + quad * 4) = o;
        }

        __syncthreads();   // span end: all LDS writes visible, X(t+1) landed
    }
}

// ---------------------------------------------------------------------------
// FUSED TAIL (v1 + cross-head K prefetch): 16 rows/block, 512 threads,
// 256 blocks (1/CU). Best measured decoder config (R9: 385.5 us total).
// V preloaded at head top; K for head h+1 prefetched during head h.
// ---------------------------------------------------------------------------
__global__ __launch_bounds__(512) void decoder_kernel(
    const unsigned short* __restrict__ Xbf, const float* __restrict__ true_u,
    const unsigned short* __restrict__ keys, const unsigned short* __restrict__ vals,
    const int* __restrict__ nbr, const float* __restrict__ mask,
    const int* __restrict__ pp, const unsigned short* __restrict__ Wm,
    const float* __restrict__ ds_b,
    const float* __restrict__ ln1_g, const float* __restrict__ ln1_b,
    const float* __restrict__ ff_b1, const float* __restrict__ ff_b2,
    const float* __restrict__ ln2_g, const float* __restrict__ ln2_b,
    const float* __restrict__ de_b1, const float* __restrict__ de_b2,
    const float* __restrict__ de_b3, float* __restrict__ outp)
{
    __shared__ float avF[16][264];
    __shared__ float attF[16][264];
    __shared__ unsigned short abuf[16 * 256];
    __shared__ unsigned short hbuf[16 * 256];
    __shared__ int   ni_s[16][64];
    __shared__ float wtsb[16][64];
    __shared__ float psum[16][8], psq[16][8];
    __shared__ float rowmax[16];
    __shared__ int   tcol[16];
    __shared__ int   pps[16];

    const int tid = threadIdx.x;
    const int w = tid >> 6, lane = tid & 63;
    const int ln = lane & 15, quad = lane >> 4;
    const int bid = blockIdx.x;
    const int b = bid & 7;                       // XCD-affine batch
    const int r0 = b * 512 + (bid >> 3) * 16;    // global row base
    const int cb = w * 32;                       // GEMM column base

    const f32x4 zero = {0.f, 0.f, 0.f, 0.f};

    // ---- init: pp values + neighbor indices ----
    if (tid < 16) pps[tid] = pp[(r0 + tid) & 511];
    #pragma unroll
    for (int j = 0; j < 2; ++j) {
        const int idx = tid * 2 + j;             // 1024 = 16*64
        const int row = idx >> 6, n = idx & 63;
        ni_s[row][n] = nbr[((r0 + row) & 511) * 64 + n];
    }
    __syncthreads();

    // ---- gather X rows into abuf ----
    {
        const int row = tid >> 5, c = tid & 31;
        const size_t arow = (size_t)b * Vc + pps[row];
        uint4 d = *(const uint4*)(Xbf + arow * 256 + c * 8);
        *(uint4*)&abuf[row * 256 + ((c ^ row) * 8)] = d;
    }
    __syncthreads();

    // ---- ds GEMM ----
    {
        const unsigned short* Wt = Wm;
        f32x4 acc[2]; acc[0] = zero; acc[1] = zero;
        const unsigned short* wb = Wt + (size_t)(cb + ln) * 256 + quad * 8;
        #pragma unroll
        for (int ks = 0; ks < 8; ++ks) {
            bf16x8 A = *(const bf16x8*)&abuf[hsw_chunk(ln, ks, quad)];
            #pragma unroll
            for (int ct = 0; ct < 2; ++ct) {
                bf16x8 Bv = *(const bf16x8*)(wb + (size_t)ct * 16 * 256 + ks * 32);
                acc[ct] = __builtin_amdgcn_mfma_f32_16x16x32_bf16(A, Bv, acc[ct], 0, 0, 0);
            }
        }
        __syncthreads();
        #pragma unroll
        for (int ct = 0; ct < 2; ++ct) {
            const int col = cb + ct * 16 + ln;
            const float bb = ds_b[col];
            #pragma unroll
            for (int r = 0; r < 4; ++r) {
                const int row = quad * 4 + r;
                float v = acc[ct][r] + bb;
                avF[row][col] = v;
                abuf[hsw_elem(row, col)] = f2bf(v);
            }
        }
    }
    __syncthreads();

    // ==================== transformer layers ====================
    for (int l = 0; l < Lc; ++l) {
        const unsigned short* kvb = keys + (((size_t)l * Bc + b) * Vc) * 256;
        const unsigned short* vvb = vals + (((size_t)l * Bc + b) * Vc) * 256;

        // ---- attention: rows w*2 and w*2+1 interleaved, V preloaded,
        //      K for head h+1 prefetched during head h ----
        {
            const int row0a = w * 2, row1a = w * 2 + 1;
            const int p0 = (r0 + row0a) & 511, p1 = (r0 + row1a) & 511;
            const int n = lane;
            const int vi0 = ni_s[row0a][n], vi1 = ni_s[row1a][n];
            const float m0 = mask[p0 * 64 + n], m1 = mask[p1 * 64 + n];
            const int nb4 = n >> 2, cg8 = (n & 3) * 8;
            int vrow0[4], vrow1[4];
            #pragma unroll
            for (int pass = 0; pass < 4; ++pass) {
                const int nn = pass * 16 + nb4;
                vrow0[pass] = ni_s[row0a][nn];
                vrow1[pass] = ni_s[row1a][nn];
            }
            const unsigned short* kr0 = kvb + (size_t)vi0 * 256;
            const unsigned short* kr1 = kvb + (size_t)vi1 * 256;
            // K for head 0
            uint4 ku0[4], ku1[4];
            #pragma unroll
            for (int j = 0; j < 4; ++j) {
                ku0[j] = *(const uint4*)(kr0 + j * 8);
                ku1[j] = *(const uint4*)(kr1 + j * 8);
            }
            for (int h = 0; h < 8; ++h) {
                // V preload (independent of softmax -> overlaps score+softmax)
                uint4 vu0[4], vu1[4];
                #pragma unroll
                for (int pass = 0; pass < 4; ++pass) {
                    vu0[pass] = *(const uint4*)(vvb + (size_t)vrow0[pass] * 256 + h * 32 + cg8);
                    vu1[pass] = *(const uint4*)(vvb + (size_t)vrow1[pass] * 256 + h * 32 + cg8);
                }
                // K prefetch for head h+1 (waitcnt lands at loop bottom copy)
                uint4 kn0[4], kn1[4];
                if (h < 7) {
                    #pragma unroll
                    for (int j = 0; j < 4; ++j) {
                        kn0[j] = *(const uint4*)(kr0 + (h + 1) * 32 + j * 8);
                        kn1[j] = *(const uint4*)(kr1 + (h + 1) * 32 + j * 8);
                    }
                }
                // q for both rows (broadcast LDS reads)
                float q0[32], q1[32];
                #pragma unroll
                for (int j = 0; j < 8; ++j) {
                    float4 t0 = *(const float4*)&avF[row0a][h * 32 + j * 4];
                    float4 t1 = *(const float4*)&avF[row1a][h * 32 + j * 4];
                    q0[j * 4 + 0] = t0.x; q0[j * 4 + 1] = t0.y;
                    q0[j * 4 + 2] = t0.z; q0[j * 4 + 3] = t0.w;
                    q1[j * 4 + 0] = t1.x; q1[j * 4 + 1] = t1.y;
                    q1[j * 4 + 2] = t1.z; q1[j * 4 + 3] = t1.w;
                }
                // two independent score chains from prefetched K
                float s0 = 0.f, s1 = 0.f;
                #pragma unroll
                for (int j = 0; j < 4; ++j) {
                    uint4 u0 = ku0[j];
                    uint4 u1 = ku1[j];
                    s0 += q0[j * 8 + 0] * bflo(u0.x) + q0[j * 8 + 1] * bfhi(u0.x);
                    s1 += q1[j * 8 + 0] * bflo(u1.x) + q1[j * 8 + 1] * bfhi(u1.x);
                    s0 += q0[j * 8 + 2] * bflo(u0.y) + q0[j * 8 + 3] * bfhi(u0.y);
                    s1 += q1[j * 8 + 2] * bflo(u1.y) + q1[j * 8 + 3] * bfhi(u1.y);
                    s0 += q0[j * 8 + 4] * bflo(u0.z) + q0[j * 8 + 5] * bfhi(u0.z);
                    s1 += q1[j * 8 + 4] * bflo(u1.z) + q1[j * 8 + 5] * bfhi(u1.z);
                    s0 += q0[j * 8 + 6] * bflo(u0.w) + q0[j * 8 + 7] * bfhi(u0.w);
                    s1 += q1[j * 8 + 6] * bflo(u1.w) + q1[j * 8 + 7] * bfhi(u1.w);
                }
                s0 = (s0 - m0) * 0.17677669529663689f;
                s1 = (s1 - m1) * 0.17677669529663689f;
                // interleaved softmax butterflies
                float mx0 = s0, mx1 = s1;
                #pragma unroll
                for (int off = 32; off >= 1; off >>= 1) {
                    mx0 = fmaxf(mx0, __shfl_xor(mx0, off));
                    mx1 = fmaxf(mx1, __shfl_xor(mx1, off));
                }
                float e0 = expf(s0 - mx0), e1 = expf(s1 - mx1);
                float sum0 = e0, sum1 = e1;
                #pragma unroll
                for (int off = 32; off >= 1; off >>= 1) {
                    sum0 += __shfl_xor(sum0, off);
                    sum1 += __shfl_xor(sum1, off);
                }
                wtsb[row0a][n] = e0 / sum0;
                wtsb[row1a][n] = e1 / sum1;
                // PV with preloaded V
                float a0[8], a1[8];
                #pragma unroll
                for (int j = 0; j < 8; ++j) { a0[j] = 0.f; a1[j] = 0.f; }
                #pragma unroll
                for (int pass = 0; pass < 4; ++pass) {
                    const int nn = pass * 16 + nb4;
                    const float w0 = wtsb[row0a][nn], w1 = wtsb[row1a][nn];
                    uint4 u0 = vu0[pass];
                    uint4 u1 = vu1[pass];
                    a0[0] += w0 * bflo(u0.x); a0[1] += w0 * bfhi(u0.x);
                    a1[0] += w1 * bflo(u1.x); a1[1] += w1 * bfhi(u1.x);
                    a0[2] += w0 * bflo(u0.y); a0[3] += w0 * bfhi(u0.y);
                    a1[2] += w1 * bflo(u1.y); a1[3] += w1 * bfhi(u1.y);
                    a0[4] += w0 * bflo(u0.z); a0[5] += w0 * bfhi(u0.z);
                    a1[4] += w1 * bflo(u1.z); a1[5] += w1 * bfhi(u1.z);
                    a0[6] += w0 * bflo(u0.w); a0[7] += w0 * bfhi(u0.w);
                    a1[6] += w1 * bflo(u1.w); a1[7] += w1 * bfhi(u1.w);
                }
                #pragma unroll
                for (int off = 4; off <= 32; off <<= 1)
                    #pragma unroll
                    for (int j = 0; j < 8; ++j) {
                        a0[j] += __shfl_xor(a0[j], off);
                        a1[j] += __shfl_xor(a1[j], off);
                    }
                if (nb4 == 0)
                    #pragma unroll
                    for (int j = 0; j < 8; ++j) {
                        attF[row0a][h * 32 + cg8 + j] = a0[j];
                        attF[row1a][h * 32 + cg8 + j] = a1[j];
                    }
                // rotate prefetched K into place
                if (h < 7) {
                    #pragma unroll
                    for (int j = 0; j < 4; ++j) { ku0[j] = kn0[j]; ku1[j] = kn1[j]; }
                }
            }
            // LN1 for both rows (in-wave)
            #pragma unroll
            for (int rr = 0; rr < 2; ++rr) {
                const int row = w * 2 + rr;
                const int c0 = lane * 4;
                float x[4];
                float sl = 0.f, ql = 0.f;
                #pragma unroll
                for (int j = 0; j < 4; ++j) {
                    x[j] = avF[row][c0 + j] + attF[row][c0 + j];
                    sl += x[j]; ql += x[j] * x[j];
                }
                #pragma unroll
                for (int off = 32; off >= 1; off >>= 1) {
                    sl += __shfl_xor(sl, off);
                    ql += __shfl_xor(ql, off);
                }
                const float mu = sl * (1.0f / 256.0f);
                const float var = ql * (1.0f / 256.0f) - mu * mu;
                const float rstd = 1.0f / sqrtf(fmaxf(var, 0.f) + 1e-5f);
                #pragma unroll
                for (int j = 0; j < 4; ++j) {
                    const int col = c0 + j;
                    float o = (x[j] - mu) * rstd * ln1_g[l * 256 + col] + ln1_b[l * 256 + col];
                    avF[row][col] = o;
                    abuf[hsw_elem(row, col)] = f2bf(o);
                }
            }
        }
        __syncthreads();

        // ---- ff stage A: T1 = relu(abuf @ W1 + b1) -> hbuf ----
        {
            const unsigned short* W1 = Wm + (size_t)(1 + l) * 65536;
            f32x4 acc[2]; acc[0] = zero; acc[1] = zero;
            const unsigned short* wb = W1 + (size_t)(cb + ln) * 256 + quad * 8;
            #pragma unroll
            for (int ks = 0; ks < 8; ++ks) {
                bf16x8 A = *(const bf16x8*)&abuf[hsw_chunk(ln, ks, quad)];
                #pragma unroll
                for (int ct = 0; ct < 2; ++ct) {
                    bf16x8 Bv = *(const bf16x8*)(wb + (size_t)ct * 16 * 256 + ks * 32);
                    acc[ct] = __builtin_amdgcn_mfma_f32_16x16x32_bf16(A, Bv, acc[ct], 0, 0, 0);
                }
            }
            #pragma unroll
            for (int ct = 0; ct < 2; ++ct) {
                const int col = cb + ct * 16 + ln;
                const float bb = ff_b1[l * 256 + col];
                #pragma unroll
                for (int r = 0; r < 4; ++r) {
                    const int row = quad * 4 + r;
                    hbuf[hsw_elem(row, col)] = f2bf(fmaxf(acc[ct][r] + bb, 0.f));
                }
            }
        }
        __syncthreads();

        // ---- ff stage B + residual + LN2 ----
        {
            const unsigned short* W2 = Wm + (size_t)(3 + l) * 65536;
            f32x4 acc[2]; acc[0] = zero; acc[1] = zero;
            const unsigned short* wb = W2 + (size_t)(cb + ln) * 256 + quad * 8;
            #pragma unroll
            for (int ks = 0; ks < 8; ++ks) {
                bf16x8 A = *(const bf16x8*)&hbuf[hsw_chunk(ln, ks, quad)];
                #pragma unroll
                for (int ct = 0; ct < 2; ++ct) {
                    bf16x8 Bv = *(const bf16x8*)(wb + (size_t)ct * 16 * 256 + ks * 32);
                    acc[ct] = __builtin_amdgcn_mfma_f32_16x16x32_bf16(A, Bv, acc[ct], 0, 0, 0);
                }
            }
            float vv[2][4];
            #pragma unroll
            for (int ct = 0; ct < 2; ++ct) {
                const int col = cb + ct * 16 + ln;
                const float bb = ff_b2[l * 256 + col];
                #pragma unroll
                for (int r = 0; r < 4; ++r) {
                    const int row = quad * 4 + r;
                    vv[ct][r] = acc[ct][r] + bb + avF[row][col];
                }
            }
            #pragma unroll
            for (int r = 0; r < 4; ++r) {
                float sl = vv[0][r] + vv[1][r];
                float ql = vv[0][r] * vv[0][r] + vv[1][r] * vv[1][r];
                #pragma unroll
                for (int off = 8; off >= 1; off >>= 1) {
                    sl += __shfl_xor(sl, off);
                    ql += __shfl_xor(ql, off);
                }
                if (ln == 0) {
                    const int row = quad * 4 + r;
                    psum[row][w] = sl; psq[row][w] = ql;
                }
            }
            __syncthreads();
            #pragma unroll
            for (int r = 0; r < 4; ++r) {
                const int row = quad * 4 + r;
                float sl = 0.f, ql = 0.f;
                #pragma unroll
                for (int j = 0; j < 8; ++j) { sl += psum[row][j]; ql += psq[row][j]; }
                const float mu = sl * (1.0f / 256.0f);
                const float var = ql * (1.0f / 256.0f) - mu * mu;
                const float rstd = 1.0f / sqrtf(fmaxf(var, 0.f) + 1e-5f);
                #pragma unroll
                for (int ct = 0; ct < 2; ++ct) {
                    const int col = cb + ct * 16 + ln;
                    float o = (vv[ct][r] - mu) * rstd * ln2_g[l * 256 + col] + ln2_b[l * 256 + col];
                    avF[row][col] = o;
                    abuf[hsw_elem(row, col)] = f2bf(o);
                }
            }
        }
        __syncthreads();
    }

    // ==================== decoder + loss ====================
    {
        const unsigned short* W1 = Wm + (size_t)5 * 65536;
        f32x4 acc[2]; acc[0] = zero; acc[1] = zero;
        const unsigned short* wb = W1 + (size_t)(cb + ln) * 256 + quad * 8;
        #pragma unroll
        for (int ks = 0; ks < 8; ++ks) {
            bf16x8 A = *(const bf16x8*)&abuf[hsw_chunk(ln, ks, quad)];
            #pragma unroll
            for (int ct = 0; ct < 2; ++ct) {
                bf16x8 Bv = *(const bf16x8*)(wb + (size_t)ct * 16 * 256 + ks * 32);
                acc[ct] = __builtin_amdgcn_mfma_f32_16x16x32_bf16(A, Bv, acc[ct], 0, 0, 0);
            }
        }
        #pragma unroll
        for (int ct = 0; ct < 2; ++ct) {
            const int col = cb + ct * 16 + ln;
            const float bb = de_b1[col];
            #pragma unroll
            for (int r = 0; r < 4; ++r) {
                const int row = quad * 4 + r;
                hbuf[hsw_elem(row, col)] = f2bf(fmaxf(acc[ct][r] + bb, 0.f));
            }
        }
    }
    __syncthreads();

    {
        const unsigned short* W2 = Wm + (size_t)6 * 65536;
        f32x4 acc[2]; acc[0] = zero; acc[1] = zero;
        const unsigned short* wb = W2 + (size_t)(cb + ln) * 256 + quad * 8;
        #pragma unroll
        for (int ks = 0; ks < 8; ++ks) {
            bf16x8 A = *(const bf16x8*)&hbuf[hsw_chunk(ln, ks, quad)];
            #pragma unroll
            for (int ct = 0; ct < 2; ++ct) {
                bf16x8 Bv = *(const bf16x8*)(wb + (size_t)ct * 16 * 256 + ks * 32);
                acc[ct] = __builtin_amdgcn_mfma_f32_16x16x32_bf16(A, Bv, acc[ct], 0, 0, 0);
            }
        }
        __syncthreads();
        #pragma unroll
        for (int ct = 0; ct < 2; ++ct) {
            const int col = cb + ct * 16 + ln;
            const float bb = de_b2[col];
            #pragma unroll
            for (int r = 0; r < 4; ++r) {
                const int row = quad * 4 + r;
                hbuf[hsw_elem(row, col)] = f2bf(fmaxf(acc[ct][r] + bb, 0.f));
            }
        }
    }
    __syncthreads();

    {
        const unsigned short* W3 = Wm + (size_t)7 * 65536;
        const int cb3 = w * 16;
        f32x4 a3 = zero;
        const unsigned short* wb = W3 + (size_t)(cb3 + ln) * 256 + quad * 8;
        #pragma unroll
        for (int ks = 0; ks < 8; ++ks) {
            bf16x8 A = *(const bf16x8*)&hbuf[hsw_chunk(ln, ks, quad)];
            bf16x8 Bv = *(const bf16x8*)(wb + ks * 32);
            a3 = __builtin_amdgcn_mfma_f32_16x16x32_bf16(A, Bv, a3, 0, 0, 0);
        }
        float lg[4];
        const float bb = de_b3[cb3 + ln];
        #pragma unroll
        for (int r = 0; r < 4; ++r) lg[r] = a3[r] + bb;

        #pragma unroll
        for (int r = 0; r < 4; ++r) {
            float m = lg[r];
            #pragma unroll
            for (int off = 8; off >= 1; off >>= 1) m = fmaxf(m, __shfl_xor(m, off));
            if (ln == 0) psum[quad * 4 + r][w] = m;
        }
        __syncthreads();
        if (tid < 16) {
            float m = psum[tid][0];
            #pragma unroll
            for (int j = 1; j < 8; ++j) m = fmaxf(m, psum[tid][j]);
            rowmax[tid] = m;
            float tu = true_u[(size_t)b * Vc + pps[tid]];
            int t = (int)floorf(tu * 128.0f);
            tcol[tid] = t < 0 ? 0 : (t > 127 ? 127 : t);
        }
        __syncthreads();
        #pragma unroll
        for (int r = 0; r < 4; ++r) {
            const int row = quad * 4 + r;
            const float mx = rowmax[row];
            const int t = tcol[row];
            float e = expf(lg[r] - mx);
            float xt = ((cb3 + ln) == t) ? lg[r] : 0.f;
            #pragma unroll
            for (int off = 8; off >= 1; off >>= 1) {
                e += __shfl_xor(e, off);
                xt += __shfl_xor(xt, off);
            }
            if (ln == 0) { psum[row][w] = e; psq[row][w] = xt; }
        }
        __syncthreads();
        float contrib = 0.f;
        if (tid < 16) {
            float sum = 0.f, xt = 0.f;
            #pragma unroll
            for (int j = 0; j < 8; ++j) { sum += psum[tid][j]; xt += psq[tid][j]; }
            const float lp = logf(128.0f) + (xt - rowmax[tid]) - logf(sum);
            contrib = -lp;
        }
        if (w == 0) {
            #pragma unroll
            for (int off = 32; off >= 1; off >>= 1) contrib += __shfl_xor(contrib, off);
            if (lane == 0) atomicAdd(&outp[b], contrib);
        }
    }
}

// ---------------------------------------------------------------------------
extern "C" void kernel_launch(void* const* d_in, const int* in_sizes, int n_in,
                              void* d_out, int out_size, void* d_ws, size_t ws_size,
                              hipStream_t stream)
{
    (void)in_sizes; (void)n_in; (void)out_size; (void)ws_size;

    const float* encoded        = (const float*)d_in[0];
    const float* true_u         = (const float*)d_in[1];
    const float* attn_mask      = (const float*)d_in[2];
    const int*   pred_points    = (const int*)d_in[3];
    const int*   neighbor_index = (const int*)d_in[4];
    const float* kW1 = (const float*)d_in[5];
    const float* kb1 = (const float*)d_in[6];
    const float* kW2 = (const float*)d_in[7];
    const float* kb2 = (const float*)d_in[8];
    const float* kW3 = (const float*)d_in[9];
    const float* kb3 = (const float*)d_in[10];
    const float* vW1 = (const float*)d_in[11];
    const float* vb1 = (const float*)d_in[12];
    const float* vW2 = (const float*)d_in[13];
    const float* vb2 = (const float*)d_in[14];
    const float* vW3 = (const float*)d_in[15];
    const float* vb3 = (const float*)d_in[16];
    const float* ds_W  = (const float*)d_in[17];
    const float* ds_b  = (const float*)d_in[18];
    const float* ln1_g = (const float*)d_in[19];
    const float* ln1_b = (const float*)d_in[20];
    const float* ff_W1 = (const float*)d_in[21];
    const float* ff_b1 = (const float*)d_in[22];
    const float* ff_W2 = (const float*)d_in[23];
    const float* ff_b2 = (const float*)d_in[24];
    const float* ln2_g = (const float*)d_in[25];
    const float* ln2_b = (const float*)d_in[26];
    const float* de_W1 = (const float*)d_in[27];
    const float* de_b1 = (const float*)d_in[28];
    const float* de_W2 = (const float*)d_in[29];
    const float* de_b2 = (const float*)d_in[30];
    const float* de_W3 = (const float*)d_in[31];
    const float* de_b3 = (const float*)d_in[32];

    float* out = (float*)d_out;

    // workspace layout
    constexpr size_t KV_ELEMS = (size_t)Lc * Bc * Hc * Vc * 32;  // 8,388,608
    unsigned short* keys = (unsigned short*)d_ws;            // bf16 [l][b][v][256]
    unsigned short* vals = keys + KV_ELEMS;
    unsigned short* Xbf  = vals + KV_ELEMS;                  // 16384 x 256 bf16
    unsigned short* W1t  = Xbf + (size_t)ROWS_KV * 256;      // 32 nets x [256][256]
    unsigned short* W2t  = W1t + (size_t)32 * 65536;
    unsigned short* W3t  = W2t + (size_t)32 * 65536;         // 32 nets x [32][256]
    unsigned short* Wm   = W3t + (size_t)32 * 8192;          // 8 slots x 65536

    (void)hipMemsetAsync(out, 0, Bc * sizeof(float), stream);

    // prep (single launch: transposes + X conversion; 64 conv slices)
    prep_all_kernel<<<dim3(8, 8, 168), 256, 0, stream>>>(
        kW1, vW1, kW2, vW2, kW3, vW3,
        ds_W, ff_W1, ff_W2, de_W1, de_W2, de_W3, encoded,
        W1t, W2t, W3t, Wm, Xbf);

    // KV MLPs v11: 8 rg x 16 (l,h) x {k,v} = 256 blocks, 512 thr, 1/CU
    kv_mfma_kernel<<<dim3(8, 16, 2), 512, 0, stream>>>(
        Xbf, true_u, W1t, W2t, W3t, kW1, vW1,
        kb1, kb2, kb3, vb1, vb2, vb3, keys, vals);

    // fused tail v1 + K-prefetch: 256 blocks x 16 rows, 512 thr
    decoder_kernel<<<dim3(ROWS_AT / 16), 512, 0, stream>>>(
        Xbf, true_u, keys, vals, neighbor_index, attn_mask, pred_points, Wm,
        ds_b, ln1_g, ln1_b, ff_b1, ff_b2, ln2_g, ln2_b,
        de_b1, de_b2, de_b3, out);
}